// Round 7
// baseline (765.029 us; speedup 1.0000x reference)
//
#include <hip/hip_runtime.h>

typedef _Float16 F16;
typedef __attribute__((ext_vector_type(8))) _Float16 f16x8;
typedef __attribute__((ext_vector_type(4))) _Float16 f16x4;
typedef __attribute__((ext_vector_type(16))) float f32x16;

constexpr int NTOK = 8192;   // B*T
constexpr int C    = 1024;   // d_model
constexpr int FF   = 2048;   // d_ff
constexpr int NE   = 8;      // experts
constexpr int NRT  = 72;     // max routed 256-row tiles: 16384/256 + 8
constexpr int NST  = 32;     // shared-expert tiles: 8192/256
constexpr int MAXT = NRT + NST;     // 104
constexpr int SBASE = NRT * 256;    // shared rows start here in H/Y
constexpr int ROWS = SBASE + NTOK;  // 26624

#define MI_CNT 0
#define MI_CUR 8
#define MI_BASE 16
#define MI_TE 32
#define MI_TR (32 + MAXT)

__device__ __forceinline__ void gload16(const void* g, void* l) {
  __builtin_amdgcn_global_load_lds(
      (__attribute__((address_space(1))) void*)g,
      (__attribute__((address_space(3))) void*)l, 16, 0, 0);
}
#define VMCNT4() asm volatile("s_waitcnt vmcnt(4)" ::: "memory")
#define VMCNT0() asm volatile("s_waitcnt vmcnt(0)" ::: "memory")
#define BARR()   __builtin_amdgcn_s_barrier()
#define PRIO1()  __builtin_amdgcn_s_setprio(1)
#define PRIO0()  __builtin_amdgcn_s_setprio(0)

// ------- transpose+cast: src [K][N] fp32 -> dst [N'][K] fp16 ----------------
// MODE 0: N'=N (w_down). MODE 1: gate/up 32-col interleave into WGU:
//   n' = ((n>>5)<<6) | (sel<<5) | (n&31);  z = e*2+sel, e==8 -> shared weights
template <int MODE>
__global__ __launch_bounds__(256) void k_cast_w(const float* __restrict__ w8a,
                                                const float* __restrict__ w1a,
                                                const float* __restrict__ w8b,
                                                const float* __restrict__ w1b,
                                                F16* __restrict__ dst, int K, int N) {
  int z = blockIdx.z;
  const float* src; F16* d; int sel = 0;
  if (MODE == 1) {
    int e = z >> 1; sel = z & 1;
    src = sel ? ((e < NE) ? w8b + (size_t)e * K * N : w1b)
              : ((e < NE) ? w8a + (size_t)e * K * N : w1a);
    d = dst + (size_t)e * 2 * N * K;
  } else {
    src = (z < NE) ? (w8a + (size_t)z * K * N) : w1a;
    d = dst + (size_t)z * N * K;
  }
  __shared__ float t[64][33];
  int n0 = blockIdx.x * 32, k0 = blockIdx.y * 64;
  int tx = threadIdx.x & 31, ty = threadIdx.x >> 5;
#pragma unroll
  for (int i = 0; i < 8; i++)
    t[ty + i * 8][tx] = src[(size_t)(k0 + ty + i * 8) * N + n0 + tx];
  __syncthreads();
  int wx = threadIdx.x & 63, wy = threadIdx.x >> 6;
#pragma unroll
  for (int i = 0; i < 8; i++) {
    int n = n0 + wy + i * 4;
    size_t row = (MODE == 1) ? (size_t)(((n >> 5) << 6) | (sel << 5) | (n & 31))
                             : (size_t)n;
    d[row * K + k0 + wx] = (F16)t[wx][wy + i * 4];
  }
}

// ------- router (+fused x cast): fp64 logits, top-2, softmax ----------------
__global__ __launch_bounds__(256) void k_router(const float* __restrict__ x,
                                                const float* __restrict__ rw,
                                                F16* __restrict__ xh,
                                                int* __restrict__ meta,
                                                int* __restrict__ te0, int* __restrict__ te1,
                                                float* __restrict__ tw0, float* __restrict__ tw1) {
  __shared__ float lrw[NE * C];
  for (int i = threadIdx.x; i < NE * C / 4; i += 256)
    ((float4*)lrw)[i] = ((const float4*)rw)[i];
  __syncthreads();
  int lane = threadIdx.x & 63, wid = threadIdx.x >> 6;
  int t = blockIdx.x * 4 + wid;
  const float* xr = x + (size_t)t * C;
  float xv[16];
#pragma unroll
  for (int i = 0; i < 4; i++) {
    float4 v = ((const float4*)xr)[lane * 4 + i];
    xv[i * 4 + 0] = v.x; xv[i * 4 + 1] = v.y; xv[i * 4 + 2] = v.z; xv[i * 4 + 3] = v.w;
  }
  // fused fp32 -> fp16 cast of x
#pragma unroll
  for (int i = 0; i < 4; i++) {
    f16x4 o;
    o.x = (F16)xv[i * 4 + 0]; o.y = (F16)xv[i * 4 + 1];
    o.z = (F16)xv[i * 4 + 2]; o.w = (F16)xv[i * 4 + 3];
    ((f16x4*)(xh + (size_t)t * C))[lane * 4 + i] = o;
  }
  double lg[NE];
#pragma unroll
  for (int e = 0; e < NE; e++) {
    double s = 0.0;
#pragma unroll
    for (int i = 0; i < 16; i++)
      s += (double)xv[i] * (double)lrw[e * C + lane * 16 + i];
#pragma unroll
    for (int d = 1; d < 64; d <<= 1) s += __shfl_xor(s, d, 64);
    lg[e] = s;
  }
  double b0 = -1e300; int i0 = 0;
#pragma unroll
  for (int e = 0; e < NE; e++) if (lg[e] > b0) { b0 = lg[e]; i0 = e; }
  double b1 = -1e300; int i1 = 0;
#pragma unroll
  for (int e = 0; e < NE; e++) if (e != i0 && lg[e] > b1) { b1 = lg[e]; i1 = e; }
  float ex = __expf((float)(b1 - b0));
  float w0 = 1.f / (1.f + ex), w1 = ex / (1.f + ex);
  if (lane == 0) {
    te0[t] = i0; te1[t] = i1; tw0[t] = w0; tw1[t] = w1;
    atomicAdd(&meta[MI_CNT + i0], 1);
    atomicAdd(&meta[MI_CNT + i1], 1);
  }
}

// ---------------- scan: bases, tile map (routed + shared), pad fill ----------
__global__ __launch_bounds__(256) void k_scan(int* __restrict__ meta,
                                              int* __restrict__ rowtok) {
  __shared__ int s_cnt[NE], s_base[NE];
  if (threadIdx.x == 0) {
    int b = 0, nt = 0;
    for (int e = 0; e < NE; e++) {
      int c = meta[MI_CNT + e];
      s_cnt[e] = c; s_base[e] = b;
      meta[MI_BASE + e] = b;
      meta[MI_CUR + e] = 0;
      int tiles = (c + 255) >> 8;
      for (int t = 0; t < tiles; t++) {
        meta[MI_TE + nt] = e;
        meta[MI_TR + nt] = b + t * 256;
        nt++;
      }
      b += tiles << 8;
    }
    for (int t = nt; t < NRT; t++) meta[MI_TE + t] = -1;
    for (int t = 0; t < NST; t++) {
      meta[MI_TE + NRT + t] = NE;
      meta[MI_TR + NRT + t] = SBASE + t * 256;
    }
  }
  __syncthreads();
  for (int e = 0; e < NE; e++) {
    int c = s_cnt[e], b = s_base[e];
    int al = (c + 255) & ~255;
    for (int i = c + threadIdx.x; i < al; i += 256) rowtok[b + i] = -1;
  }
}

// ---------------- scatter tokens into expert buckets (+slot record) ---------
__global__ __launch_bounds__(256) void k_scatter(const int* __restrict__ te0,
                                                 const int* __restrict__ te1,
                                                 int* __restrict__ meta,
                                                 int* __restrict__ rowtok,
                                                 int* __restrict__ sl0,
                                                 int* __restrict__ sl1) {
  int t = blockIdx.x * 256 + threadIdx.x;
  int e0 = te0[t], e1 = te1[t];
  int p0 = atomicAdd(&meta[MI_CUR + e0], 1);
  int r0 = meta[MI_BASE + e0] + p0;
  rowtok[r0] = t; sl0[t] = r0;
  int p1 = atomicAdd(&meta[MI_CUR + e1], 1);
  int r1 = meta[MI_BASE + e1] + p1;
  rowtok[r1] = t; sl1[t] = r1;
}

// ======= unified 256x256 grouped GEMM — 32x32x16 MFMA, R6 frame =============
// BK=64, dbuf LDS, 2 barriers/tile, counted vmcnt(4) (never drains), unpinned
// interior. Per wave: 128x64 out = 4m x 2n frags of 32x32, 4 k-slices of 16.
template <bool G1>
__global__ __launch_bounds__(512, 2) void k_gemm(const F16* __restrict__ Asrc,
                                                 const F16* __restrict__ Wsrc,
                                                 F16* __restrict__ Dst,
                                                 const int* __restrict__ meta,
                                                 const int* __restrict__ rowtok) {
  constexpr int K = G1 ? C : FF;
  constexpr int NT = K / 64;
  const int e = meta[MI_TE + blockIdx.y];
  if (e < 0) return;
  const int row0 = meta[MI_TR + blockIdx.y];
  const int n0 = blockIdx.x * 256;
  const F16* WB = Wsrc + (size_t)e * (size_t)(G1 ? 2 * FF : C) * K;
  __shared__ __align__(16) F16 sA[2][256 * 64];
  __shared__ __align__(16) F16 sB[2][256 * 64];
  const int tid = threadIdx.x, lane = tid & 63, wid = tid >> 6;
  const int wm = wid >> 2, wn = wid & 3;

  // staging: instr i covers rows i*64..i*64+63; 8 threads/row, 16B chunks,
  // source chunk pre-swizzled so LDS stays linear (rule #21)
  const int srow = tid >> 3;
  const int scol = ((tid & 7) ^ (srow & 7)) << 3;
  const F16 *pa[4], *pb[4];
#pragma unroll
  for (int i = 0; i < 4; ++i) {
    const int r = i * 64 + srow;
    int arow;
    if (G1) {
      int tok = (e == NE) ? (row0 - SBASE + r) : rowtok[row0 + r];
      if (tok < 0) tok = 0;   // pad row: harmless dup, never combined
      arow = tok;
    } else {
      arow = row0 + r;
    }
    pa[i] = Asrc + (size_t)arow * K + scol;
    pb[i] = WB + (size_t)(n0 + i * 64 + srow) * K + scol;
  }
  const int ldsrow = wid * 8;

  // fragment LDS offsets (swizzled). 32x32x16 operand layout: row = lane&31,
  // k = (lane>>5)*8 + j. k-slice ks -> byte-chunk XOR (ks<<4) on elem offset.
  const int l31 = lane & 31, q2 = lane >> 5;
  int aoff[4], boff[2];
#pragma unroll
  for (int mf = 0; mf < 4; ++mf) {
    const int r = wm * 128 + mf * 32 + l31;
    aoff[mf] = r * 64 + ((q2 ^ (r & 7)) << 3);
  }
#pragma unroll
  for (int nf = 0; nf < 2; ++nf) {
    const int c = wn * 64 + nf * 32 + l31;
    boff[nf] = c * 64 + ((q2 ^ (c & 7)) << 3);
  }

  f32x16 acc[4][2];
  const f32x16 fz = {0.f, 0.f, 0.f, 0.f, 0.f, 0.f, 0.f, 0.f,
                     0.f, 0.f, 0.f, 0.f, 0.f, 0.f, 0.f, 0.f};
#pragma unroll
  for (int i = 0; i < 4; ++i) { acc[i][0] = fz; acc[i][1] = fz; }

  // prologue: stage tile 0 (8 loads)
#pragma unroll
  for (int i = 0; i < 4; ++i) {
    gload16(pa[i], &sA[0][(i * 64 + ldsrow) * 64]);
    gload16(pb[i], &sB[0][(i * 64 + ldsrow) * 64]);
  }

  for (int t = 0; t < NT; ++t) {
    const F16* sAc = sA[t & 1];
    const F16* sBc = sB[t & 1];
    F16* sAn = sA[(t + 1) & 1];
    F16* sBn = sB[(t + 1) & 1];
    const int gk = (t + 1) * 64;
    const bool st = (t + 1 < NT);

    // stage next-tile A (4 loads), then counted wait: completes tile t's 8,
    // keeps the 4 A-loads of t+1 in flight across the barrier.
    if (st) {
#pragma unroll
      for (int i = 0; i < 4; ++i)
        gload16(pa[i] + gk, &sAn[(i * 64 + ldsrow) * 64]);
      VMCNT4();
    } else {
      VMCNT0();
    }
    BARR();   // tile t visible to all waves

#pragma unroll
    for (int ks = 0; ks < 4; ++ks) {
      f16x8 av[4], bv[2];
#pragma unroll
      for (int mf = 0; mf < 4; ++mf)
        av[mf] = *(const f16x8*)&sAc[aoff[mf] ^ (ks << 4)];
#pragma unroll
      for (int nf = 0; nf < 2; ++nf)
        bv[nf] = *(const f16x8*)&sBc[boff[nf] ^ (ks << 4)];
      if (st && ks == 1) {
        gload16(pb[0] + gk, &sBn[ldsrow * 64]);
        gload16(pb[1] + gk, &sBn[(64 + ldsrow) * 64]);
      }
      if (st && ks == 2) {
        gload16(pb[2] + gk, &sBn[(128 + ldsrow) * 64]);
        gload16(pb[3] + gk, &sBn[(192 + ldsrow) * 64]);
      }
      PRIO1();
#pragma unroll
      for (int mf = 0; mf < 4; ++mf) {
        acc[mf][0] = __builtin_amdgcn_mfma_f32_32x32x16_f16(av[mf], bv[0], acc[mf][0], 0, 0, 0);
        acc[mf][1] = __builtin_amdgcn_mfma_f32_32x32x16_f16(av[mf], bv[1], acc[mf][1], 0, 0, 0);
      }
      PRIO0();
    }

    if (st) BARR();   // read-complete: next iter's staging overwrites buf cur
  }

  // epilogue. C/D layout: col = lane&31, row = (reg&3) + 8*(reg>>2) + 4*q2
  if (G1) {
    // nf=0 -> gate 32-block, nf=1 -> up 32-block (32-granular WGU interleave)
    const int ocol = (n0 >> 1) + wn * 32 + l31;
#pragma unroll
    for (int mf = 0; mf < 4; ++mf)
#pragma unroll
      for (int reg = 0; reg < 16; ++reg) {
        const int orow = row0 + wm * 128 + mf * 32 + (reg & 3) + 8 * (reg >> 2) + 4 * q2;
        const float gv = acc[mf][0][reg], uv = acc[mf][1][reg];
        const float h = gv / (1.f + __expf(-gv)) * uv;
        Dst[(size_t)orow * FF + ocol] = (F16)h;
      }
  } else {
#pragma unroll
    for (int mf = 0; mf < 4; ++mf)
#pragma unroll
      for (int nf = 0; nf < 2; ++nf) {
        const int gcol = n0 + wn * 64 + nf * 32 + l31;
#pragma unroll
        for (int reg = 0; reg < 16; ++reg) {
          const int grow = row0 + wm * 128 + mf * 32 + (reg & 3) + 8 * (reg >> 2) + 4 * q2;
          Dst[(size_t)grow * C + gcol] = (F16)acc[mf][nf][reg];
        }
      }
  }
}

// ---------------- combine: out = w0*Y[r0] + w1*Y[r1] + Y[shared] ------------
__global__ __launch_bounds__(256) void k_combine(const F16* __restrict__ Y,
                                                 const int* __restrict__ sl0,
                                                 const int* __restrict__ sl1,
                                                 const float* __restrict__ tw0,
                                                 const float* __restrict__ tw1,
                                                 float* __restrict__ out) {
  int idx = blockIdx.x * 256 + threadIdx.x;
  int t = idx >> 7, cg = idx & 127;
  int r0 = sl0[t], r1 = sl1[t];
  float w0 = tw0[t], w1 = tw1[t];
  f16x8 y0 = *(const f16x8*)&Y[(size_t)r0 * C + cg * 8];
  f16x8 y1 = *(const f16x8*)&Y[(size_t)r1 * C + cg * 8];
  f16x8 ys = *(const f16x8*)&Y[(size_t)(SBASE + t) * C + cg * 8];
  float o[8];
#pragma unroll
  for (int j = 0; j < 8; j++)
    o[j] = w0 * (float)y0[j] + w1 * (float)y1[j] + (float)ys[j];
  float* op = out + (size_t)t * C + cg * 8;
  ((float4*)op)[0] = make_float4(o[0], o[1], o[2], o[3]);
  ((float4*)op)[1] = make_float4(o[4], o[5], o[6], o[7]);
}

// ---------------- host launch ----------------
extern "C" void kernel_launch(void* const* d_in, const int* in_sizes, int n_in,
                              void* d_out, int out_size, void* d_ws, size_t ws_size,
                              hipStream_t stream) {
  const float* x  = (const float*)d_in[0];
  const float* rw = (const float*)d_in[1];
  const float* wgate = (const float*)d_in[2];
  const float* wup   = (const float*)d_in[3];
  const float* wdown = (const float*)d_in[4];
  const float* sg = (const float*)d_in[5];
  const float* su = (const float*)d_in[6];
  const float* sd = (const float*)d_in[7];
  float* out = (float*)d_out;

  char* ws = (char*)d_ws;
  size_t o = 0;
  auto alloc = [&](size_t bytes) -> void* {
    void* p = ws + o;
    o += (bytes + 255) & ~(size_t)255;
    return p;
  };
  F16* xh  = (F16*)alloc((size_t)NTOK * C * 2);
  F16* WGU = (F16*)alloc((size_t)9 * 2 * FF * C * 2);
  F16* WD  = (F16*)alloc((size_t)9 * C * FF * 2);
  F16* Hb  = (F16*)alloc((size_t)ROWS * FF * 2);
  int* rowtok = (int*)alloc((size_t)SBASE * 4);
  int* meta = (int*)alloc(2048);
  int* te0 = (int*)alloc((size_t)NTOK * 4);
  int* te1 = (int*)alloc((size_t)NTOK * 4);
  float* tw0 = (float*)alloc((size_t)NTOK * 4);
  float* tw1 = (float*)alloc((size_t)NTOK * 4);
  int* sl0 = (int*)alloc((size_t)NTOK * 4);
  int* sl1 = (int*)alloc((size_t)NTOK * 4);
  if (o > ws_size) return;
  F16* Yb = WGU;   // overlay: WGU dead after gemm1; Y (54.5MB) < WGU (75.5MB)

  hipMemsetAsync(meta, 0, 1024, stream);
  k_cast_w<1><<<dim3(FF / 32, C / 64, 18), 256, 0, stream>>>(wgate, sg, wup, su, WGU, C, FF);
  k_cast_w<0><<<dim3(C / 32, FF / 64, 9), 256, 0, stream>>>(wdown, sd, nullptr, nullptr, WD, FF, C);
  k_router<<<NTOK / 4, 256, 0, stream>>>(x, rw, xh, meta, te0, te1, tw0, tw1);
  k_scan<<<1, 256, 0, stream>>>(meta, rowtok);
  k_scatter<<<NTOK / 256, 256, 0, stream>>>(te0, te1, meta, rowtok, sl0, sl1);
  k_gemm<true><<<dim3(2 * FF / 256, MAXT), 512, 0, stream>>>(xh, WGU, Hb, meta, rowtok);
  k_gemm<false><<<dim3(C / 256, MAXT), 512, 0, stream>>>(Hb, WD, Yb, meta, rowtok);
  k_combine<<<NTOK * (C / 8) / 256, 256, 0, stream>>>(Yb, sl0, sl1, tw0, tw1, out);
}